// Round 1
// baseline (3677.731 us; speedup 1.0000x reference)
//
#include <hip/hip_runtime.h>
#include <math.h>

// Problem constants
#define NB   16          // batch
#define CC   256         // latent dim
#define HH   32
#define WW   32
#define NPTS 16384       // NB*HH*WW
#define KK   8192        // num codebook vectors
#define Z_OUT 4194304    // NPTS*CC (z_q_out elements)
// d_out layout: [0, Z_OUT) z_q_out (BCHW), [Z_OUT, Z_OUT+NPTS) idx as float, [Z_OUT+NPTS] loss

// ws layout (floats):
//   [0]                 loss accumulator
//   [64 .. 64+16384)    znorm[n]
//   [16448 .. +8192)    enorm[k]
//   [32768 .. +2097152) eT[c][k]  (transposed embedding, 8 MB)
#define WS_ZNORM 64
#define WS_ENORM 16448
#define WS_ET    32768

// ---------------- K0a: znorm + zero loss accumulator ----------------
__global__ void k_znorm(const float* __restrict__ z, float* __restrict__ znorm,
                        float* __restrict__ lossAcc) {
    const int n  = blockIdx.x * 256 + threadIdx.x;   // 64 blocks x 256
    const int b  = n >> 10, hw = n & 1023;
    const float* p = z + (size_t)b * 262144 + hw;    // z[b, c, hw]: stride 1024 over c
    float s = 0.0f;
#pragma unroll 8
    for (int c = 0; c < CC; ++c) {
        float v = p[(size_t)c * 1024];
        s = fmaf(v, v, s);
    }
    znorm[n] = s;
    if (n == 0) lossAcc[0] = 0.0f;
}

// ---------------- K0b: transpose emb[k][c] -> eT[c][k] ----------------
__global__ void k_transpose(const float* __restrict__ emb, float* __restrict__ eT) {
    __shared__ float ts[64][65];                      // +1 pad breaks bank conflicts
    const int k0 = blockIdx.x * 64;                   // 128 blocks
    const int c0 = blockIdx.y * 64;                   // 4 blocks
    const int tid = threadIdx.x;                      // 256
#pragma unroll
    for (int p = 0; p < 4; ++p) {
        int u = p * 256 + tid;                        // 0..1023
        int i = u >> 4, j4 = (u & 15) << 2;           // k-row, c-quad
        float4 v = *(const float4*)(emb + (size_t)(k0 + i) * CC + c0 + j4);
        ts[i][j4 + 0] = v.x; ts[i][j4 + 1] = v.y; ts[i][j4 + 2] = v.z; ts[i][j4 + 3] = v.w;
    }
    __syncthreads();
#pragma unroll
    for (int p = 0; p < 4; ++p) {
        int u = p * 256 + tid;
        int j = u >> 4, i4 = (u & 15) << 2;           // c-col, k-quad
        float4 v = make_float4(ts[i4 + 0][j], ts[i4 + 1][j], ts[i4 + 2][j], ts[i4 + 3][j]);
        *(float4*)(eT + (size_t)(c0 + j) * KK + k0 + i4) = v;
    }
}

// ---------------- K0c: enorm (one wave per codebook row) ----------------
__global__ void k_enorm(const float* __restrict__ emb, float* __restrict__ enorm) {
    const int w = threadIdx.x >> 6, lane = threadIdx.x & 63;
    const int k = blockIdx.x * 4 + w;                 // 2048 blocks x 4 waves
    float4 v = *(const float4*)(emb + (size_t)k * CC + lane * 4);
    float s = v.x * v.x + v.y * v.y + v.z * v.z + v.w * v.w;
    for (int off = 32; off > 0; off >>= 1) s += __shfl_down(s, off);
    if (lane == 0) enorm[k] = s;
}

// ---------------- K1: fused distance + argmin ----------------
// grid 256 blocks (one per CU), 512 threads (8 waves = 2/SIMD).
// Block covers 64 consecutive n (lane = n offset). zs staged once (64 KB).
// Wave w handles k in [w*1024, (w+1)*1024) in 64 sets of 16; acc[16] in VGPRs.
__global__ __launch_bounds__(512, 2)
void k_argmin(const float* __restrict__ z, const float* __restrict__ eT,
              const float* __restrict__ znorm, const float* __restrict__ enorm,
              float* __restrict__ idx_out) {
    __shared__ float zs[CC * 64];                     // zs[c][m], 64 KB; reused for reduce
    const int tid = threadIdx.x;
    const int nb  = blockIdx.x << 6;                  // n base (multiple of 64)
    const int b   = nb >> 10, hw0 = nb & 1023;
    const float* zbase = z + (size_t)b * 262144 + hw0;

    // Stage z-tile: zs[c][m] = z[b, c, hw0+m]; coalesced, no bank conflicts.
#pragma unroll
    for (int p = 0; p < 8; ++p) {
        int u = (p << 9) + tid;                       // 0..4095
        int c = u >> 4, m4 = (u & 15) << 2;
        *(float4*)(zs + (c << 6) + m4) = *(const float4*)(zbase + (size_t)c * 1024 + m4);
    }
    __syncthreads();

    const int lane = tid & 63;
    const int w    = tid >> 6;                        // keep divergent-labeled -> vector e loads
    const int n    = nb + lane;
    const float zn = znorm[n];

    float bv = __builtin_inff();
    int   bi = 0;
    const int k0w = w << 10;

#pragma unroll 1
    for (int ks = 0; ks < 64; ++ks) {
        const int k0 = k0w + (ks << 4);
        const float* ep = eT + k0;                    // eT[c][k0..k0+15]
        float acc[16];
#pragma unroll
        for (int j = 0; j < 16; ++j) acc[j] = 0.0f;

#pragma unroll 4
        for (int c = 0; c < CC; ++c) {
            const float zv = zs[(c << 6) + lane];
            const float4* e4 = (const float4*)(ep + (size_t)c * KK);
            const float4 e0 = e4[0];
            const float4 e1 = e4[1];
            const float4 e2 = e4[2];
            const float4 e3 = e4[3];
            acc[0]  = fmaf(zv, e0.x, acc[0]);
            acc[1]  = fmaf(zv, e0.y, acc[1]);
            acc[2]  = fmaf(zv, e0.z, acc[2]);
            acc[3]  = fmaf(zv, e0.w, acc[3]);
            acc[4]  = fmaf(zv, e1.x, acc[4]);
            acc[5]  = fmaf(zv, e1.y, acc[5]);
            acc[6]  = fmaf(zv, e1.z, acc[6]);
            acc[7]  = fmaf(zv, e1.w, acc[7]);
            acc[8]  = fmaf(zv, e2.x, acc[8]);
            acc[9]  = fmaf(zv, e2.y, acc[9]);
            acc[10] = fmaf(zv, e2.z, acc[10]);
            acc[11] = fmaf(zv, e2.w, acc[11]);
            acc[12] = fmaf(zv, e3.x, acc[12]);
            acc[13] = fmaf(zv, e3.y, acc[13]);
            acc[14] = fmaf(zv, e3.z, acc[14]);
            acc[15] = fmaf(zv, e3.w, acc[15]);
        }

        // d = fp32((znorm + enorm) - fp32(2*dot)); 2*acc is exact, single final rounding
        const float4 en0 = *(const float4*)(enorm + k0);
        const float4 en1 = *(const float4*)(enorm + k0 + 4);
        const float4 en2 = *(const float4*)(enorm + k0 + 8);
        const float4 en3 = *(const float4*)(enorm + k0 + 12);
        const float en[16] = {en0.x, en0.y, en0.z, en0.w, en1.x, en1.y, en1.z, en1.w,
                              en2.x, en2.y, en2.z, en2.w, en3.x, en3.y, en3.z, en3.w};
#pragma unroll
        for (int j = 0; j < 16; ++j) {
            const float t = zn + en[j];
            const float d = t - (acc[j] + acc[j]);
            if (d < bv) { bv = d; bi = k0 + j; }      // k strictly ascending -> first-index ties
        }
    }

    // Cross-wave argmin reduce (reuse zs LDS after barrier)
    __syncthreads();
    float* redv = zs;                                 // [8][64]
    int*   redi = (int*)(zs + 512);                   // [8][64]
    redv[(w << 6) + lane] = bv;
    redi[(w << 6) + lane] = bi;
    __syncthreads();
    if (tid < 64) {
        float v = redv[lane];
        int   i = redi[lane];
#pragma unroll
        for (int ww = 1; ww < 8; ++ww) {
            float v2 = redv[(ww << 6) + lane];
            int   i2 = redi[(ww << 6) + lane];
            if (v2 < v || (v2 == v && i2 < i)) { v = v2; i = i2; }
        }
        idx_out[n] = (float)i;
    }
}

// ---------------- K3: gather z_q (BCHW) + loss partials ----------------
__global__ void k_gather(const float* __restrict__ z, const float* __restrict__ emb,
                         const float* __restrict__ idxf, float* __restrict__ out,
                         float* __restrict__ lossAcc) {
    __shared__ float red[256];
    const int bid = blockIdx.x;                       // 512 blocks = (b, h)
    const int b = bid >> 5, h = bid & 31;
    const int t = threadIdx.x;
    const int w_ = t & 31, cg = t >> 5;
    const int n = b * 1024 + h * 32 + w_;
    const int ki = (int)idxf[n];
    const float* ep = emb + (size_t)ki * CC;
    const size_t base = (size_t)b * 262144 + h * 32 + w_;
    float ls = 0.0f;
#pragma unroll 4
    for (int c = cg; c < CC; c += 8) {
        float e = ep[c];
        size_t a = base + (size_t)c * 1024;
        float zv = z[a];
        out[a] = e;
        float df = e - zv;
        ls = fmaf(df, df, ls);
    }
    red[t] = ls;
    __syncthreads();
    for (int s = 128; s > 0; s >>= 1) {
        if (t < s) red[t] += red[t + s];
        __syncthreads();
    }
    if (t == 0) atomicAdd(lossAcc, red[0]);
}

// ---------------- K4: finalize loss ----------------
__global__ void k_loss(const float* __restrict__ lossAcc, float* __restrict__ outLoss) {
    if (threadIdx.x == 0) {
        float m = lossAcc[0] * (1.0f / 4194304.0f);
        outLoss[0] = m + 0.25f * m;                   // (1 + BETA) * mse
    }
}

extern "C" void kernel_launch(void* const* d_in, const int* in_sizes, int n_in,
                              void* d_out, int out_size, void* d_ws, size_t ws_size,
                              hipStream_t stream) {
    const float* z   = (const float*)d_in[0];   // [16,256,32,32]
    const float* emb = (const float*)d_in[1];   // [8192,256]
    float* outf = (float*)d_out;
    float* wsf  = (float*)d_ws;

    float* lossAcc = wsf;
    float* znorm   = wsf + WS_ZNORM;
    float* enorm   = wsf + WS_ENORM;
    float* eT      = wsf + WS_ET;

    k_znorm<<<64, 256, 0, stream>>>(z, znorm, lossAcc);
    k_transpose<<<dim3(128, 4), 256, 0, stream>>>(emb, eT);
    k_enorm<<<2048, 256, 0, stream>>>(emb, enorm);
    k_argmin<<<256, 512, 0, stream>>>(z, eT, znorm, enorm, outf + Z_OUT);
    k_gather<<<512, 256, 0, stream>>>(z, emb, outf + Z_OUT, outf, lossAcc);
    k_loss<<<1, 64, 0, stream>>>(lossAcc, outf + Z_OUT + NPTS);
}